// Round 2
// baseline (1482.001 us; speedup 1.0000x reference)
//
#include <hip/hip_runtime.h>
#include <cstdint>
#include <cstddef>

#define N_ 4096
#define C_ 256

// ---------------------------------------------------------------- sq = sum x^2
__global__ __launch_bounds__(256) void k_sq(const float* __restrict__ x,
                                            float* __restrict__ sq) {
  int wave = threadIdx.x >> 6, lane = threadIdx.x & 63;
  int row = blockIdx.x * 4 + wave;            // 0..16383
  float4 v = *(const float4*)(x + (size_t)row * C_ + lane * 4);
  float s = v.x * v.x + v.y * v.y + v.z * v.z + v.w * v.w;
  s += __shfl_xor(s, 32); s += __shfl_xor(s, 16); s += __shfl_xor(s, 8);
  s += __shfl_xor(s, 4);  s += __shfl_xor(s, 2);  s += __shfl_xor(s, 1);
  if (lane == 0) sq[row] = s;
}

// ------------------------------------------------- q/k/v projections, fp32 VALU
// tile 128 rows x 128 cols, 8x8 micro, K chunked by 32
__global__ __launch_bounds__(256) void k_proj(const float* __restrict__ x,
                                              const float* __restrict__ Wq,
                                              const float* __restrict__ Wk,
                                              const float* __restrict__ Wv,
                                              const float* __restrict__ bqp,
                                              const float* __restrict__ bkp,
                                              const float* __restrict__ bvp,
                                              float* __restrict__ qf,
                                              float* __restrict__ kf,
                                              float* __restrict__ vf) {
  __shared__ float As[32 * 132];
  __shared__ float Bs[32 * 132];
  int tid = threadIdx.x;
  int m  = blockIdx.x >> 8;                    // 0..2
  int rt = (blockIdx.x >> 1) & 127;            // 0..127
  int ct = blockIdx.x & 1;                     // 0..1
  const float* W  = (m == 0) ? Wq  : ((m == 1) ? Wk  : Wv);
  const float* bb = (m == 0) ? bqp : ((m == 1) ? bkp : bvp);
  float* dst      = (m == 0) ? qf  : ((m == 1) ? kf  : vf);
  int row0 = rt * 128, col0 = ct * 128;
  int ty = tid >> 4, tx = tid & 15;

  float acc[8][8];
#pragma unroll
  for (int i = 0; i < 8; i++)
#pragma unroll
    for (int j = 0; j < 8; j++) acc[i][j] = 0.f;

#pragma unroll 1
  for (int kc = 0; kc < 8; kc++) {
    __syncthreads();
    {
      int kk = tid & 31, rg = tid >> 5;        // A: 128 rows x 32 k
#pragma unroll
      for (int rr = 0; rr < 16; rr++) {
        int r = rr * 8 + rg;
        As[kk * 132 + r] = x[(size_t)(row0 + r) * C_ + kc * 32 + kk];
      }
      int c = tid & 127, kg = tid >> 7;        // B: 32 k x 128 cols
#pragma unroll
      for (int it = 0; it < 16; it++) {
        int kk2 = it * 2 + kg;
        Bs[kk2 * 132 + c] = W[(size_t)(kc * 32 + kk2) * C_ + col0 + c];
      }
    }
    __syncthreads();
#pragma unroll
    for (int kk = 0; kk < 32; kk++) {
      float4 a0 = *(float4*)(&As[kk * 132 + ty * 8]);
      float4 a1 = *(float4*)(&As[kk * 132 + ty * 8 + 4]);
      float4 b0 = *(float4*)(&Bs[kk * 132 + tx * 8]);
      float4 b1 = *(float4*)(&Bs[kk * 132 + tx * 8 + 4]);
      float av[8], bw[8];
      *(float4*)&av[0] = a0; *(float4*)&av[4] = a1;
      *(float4*)&bw[0] = b0; *(float4*)&bw[4] = b1;
#pragma unroll
      for (int i = 0; i < 8; i++)
#pragma unroll
        for (int j = 0; j < 8; j++) acc[i][j] = fmaf(av[i], bw[j], acc[i][j]);
    }
  }
#pragma unroll
  for (int i = 0; i < 8; i++) {
    size_t r = (size_t)(row0 + ty * 8 + i) * C_;
#pragma unroll
    for (int j4 = 0; j4 < 2; j4++) {
      int c0 = col0 + tx * 8 + j4 * 4;
      float4 o;
      o.x = acc[i][j4 * 4 + 0] + bb[c0 + 0];
      o.y = acc[i][j4 * 4 + 1] + bb[c0 + 1];
      o.z = acc[i][j4 * 4 + 2] + bb[c0 + 2];
      o.w = acc[i][j4 * 4 + 3] + bb[c0 + 3];
      *(float4*)(dst + r + c0) = o;
    }
  }
}

// ------------------------------- fused distance GEMM + per-row top-16 (fp32)
// block: 128 target rows x 1024 sources (1/4 of N), 8 chunks of 128.
// grid 512 = batch(4) x tile(32) x s4(4). Partial top-16 lists -> pd/pi.
__global__ __launch_bounds__(256) void k_knn(const float* __restrict__ x,
                                             const float* __restrict__ sq,
                                             float* __restrict__ pd,
                                             int* __restrict__ pi) {
  __shared__ float uS[8448];                  // As[4224] + Bs[4224]  OR  sc[64*132]
  __shared__ float kd[2048];                  // 128 rows x 16, ascending
  __shared__ int   ki[2048];
  __shared__ float sqT[128], sqS[128];
  float* As = uS;
  float* Bs = uS + 4224;
  float* sc = uS;

  int tid = threadIdx.x;
  int b    = blockIdx.x >> 7;
  int tile = (blockIdx.x >> 2) & 31;
  int s4   = blockIdx.x & 3;
  int bN = b * N_, n0 = tile * 128, src0 = s4 * 1024;
  int ty = tid >> 4, tx = tid & 15;

#pragma unroll
  for (int i = 0; i < 8; i++) { kd[tid * 8 + i] = 1e38f; ki[tid * 8 + i] = 0; }
  if (tid < 128) sqT[tid] = sq[bN + n0 + tid];

#pragma unroll 1
  for (int ch = 0; ch < 8; ch++) {
    __syncthreads();                           // prev merge done: sc/sqS free
    if (tid < 128) sqS[tid] = sq[bN + src0 + ch * 128 + tid];

    float acc[8][8];
#pragma unroll
    for (int i = 0; i < 8; i++)
#pragma unroll
      for (int j = 0; j < 8; j++) acc[i][j] = 0.f;

#pragma unroll 1
    for (int kc = 0; kc < 8; kc++) {
      __syncthreads();
      {
        int kk = tid & 31, rg = tid >> 5;
#pragma unroll
        for (int rr = 0; rr < 16; rr++) {
          int r = rr * 8 + rg;
          As[kk * 132 + r] = x[(size_t)(bN + n0 + r) * C_ + kc * 32 + kk];
        }
        int c = tid & 127, kg = tid >> 7;
#pragma unroll
        for (int it = 0; it < 16; it++) {
          int kk2 = it * 2 + kg;
          Bs[kk2 * 132 + c] = x[(size_t)(bN + src0 + ch * 128 + c) * C_ + kc * 32 + kk2];
        }
      }
      __syncthreads();
#pragma unroll
      for (int kk = 0; kk < 32; kk++) {
        float4 a0 = *(float4*)(&As[kk * 132 + ty * 8]);
        float4 a1 = *(float4*)(&As[kk * 132 + ty * 8 + 4]);
        float4 b0 = *(float4*)(&Bs[kk * 132 + tx * 8]);
        float4 b1 = *(float4*)(&Bs[kk * 132 + tx * 8 + 4]);
        float av[8], bw[8];
        *(float4*)&av[0] = a0; *(float4*)&av[4] = a1;
        *(float4*)&bw[0] = b0; *(float4*)&bw[4] = b1;
#pragma unroll
        for (int i = 0; i < 8; i++)
#pragma unroll
          for (int j = 0; j < 8; j++) acc[i][j] = fmaf(av[i], bw[j], acc[i][j]);
      }
    }

    // two half-passes: write d2 rows to sc (union with As/Bs), then merge
#pragma unroll 1
    for (int h = 0; h < 2; h++) {
      __syncthreads();                         // compute readers / prev merge done
      if ((ty >> 3) == h) {                    // ty in [8h, 8h+8)
        int rsc = (ty - h * 8) * 8;
#pragma unroll
        for (int i = 0; i < 8; i++) {
          int rloc = ty * 8 + i;               // 0..127 within tile
#pragma unroll
          for (int j = 0; j < 8; j++) {
            int cloc = tx * 8 + j;
            float d2 = sqT[rloc] + sqS[cloc] - 2.0f * acc[i][j];
            if (n0 + rloc == src0 + ch * 128 + cloc) d2 = 1e38f;  // self
            sc[(rsc + i) * 132 + cloc] = d2;
          }
        }
      }
      __syncthreads();
      if (tid < 64) {                          // wave 0 merges 64 rows
        int row = h * 64 + tid;
        float thr = kd[row * 16 + 15];
#pragma unroll 1
        for (int c4 = 0; c4 < 32; c4++) {
          float4 d4 = *(float4*)(&sc[tid * 132 + c4 * 4]);
          float dv[4];
          *(float4*)&dv[0] = d4;
#pragma unroll
          for (int e = 0; e < 4; e++) {
            float d = dv[e];
            if (d < thr) {
              int p = 15;
              while (p > 0 && kd[row * 16 + p - 1] > d) {
                kd[row * 16 + p] = kd[row * 16 + p - 1];
                ki[row * 16 + p] = ki[row * 16 + p - 1];
                p--;
              }
              kd[row * 16 + p] = d;
              ki[row * 16 + p] = src0 + ch * 128 + c4 * 4 + e;
              thr = kd[row * 16 + 15];
            }
          }
        }
      }
    }
  }
  __syncthreads();
#pragma unroll
  for (int t = 0; t < 8; t++) {
    int e = tid * 8 + t;                       // 0..2047
    pd[(size_t)blockIdx.x * 2048 + e] = kd[e];
    pi[(size_t)blockIdx.x * 2048 + e] = ki[e];
  }
}

// ------------------------------------- merge 4 partial sorted lists -> top-16
__global__ __launch_bounds__(256) void k_kmerge(const float* __restrict__ pd,
                                                const int* __restrict__ pi,
                                                int* __restrict__ idxo) {
  int g = blockIdx.x * 256 + threadIdx.x;      // 0..16383
  int b = g >> 12, n = g & 4095;
  int tile = n >> 7, r = n & 127;
  int base[4], p[4];
  float hd[4];
#pragma unroll
  for (int s = 0; s < 4; s++) {
    base[s] = (((b * 32 + tile) * 4 + s) * 128 + r) * 16;
    p[s] = 0;
    hd[s] = pd[base[s]];
  }
#pragma unroll
  for (int k = 0; k < 16; k++) {
    int bs = 0; float bd = hd[0];
#pragma unroll
    for (int s = 1; s < 4; s++) if (hd[s] < bd) { bd = hd[s]; bs = s; }
    idxo[(size_t)g * 16 + k] = pi[base[bs] + p[bs]];
    p[bs]++;
    hd[bs] = (p[bs] < 16) ? pd[base[bs] + p[bs]] : 1e38f;
  }
}

// -------------------------------------------- gather + attention (wave/node)
__global__ __launch_bounds__(256) void k_attn(const float* __restrict__ qf,
                                              const float* __restrict__ kf,
                                              const float* __restrict__ vf,
                                              const int* __restrict__ idxv,
                                              float* __restrict__ out) {
  int wave = threadIdx.x >> 6, lane = threadIdx.x & 63;
  int g = blockIdx.x * 4 + wave;               // node 0..16383
  int bN = (g >> 12) << 12;                    // batch base row
  float4 q4 = *(const float4*)(qf + (size_t)g * C_ + lane * 4);
  int my = idxv[(size_t)g * 16 + (lane & 15)];
  const float scale = 0.17677669529663687f;    // 1/sqrt(32)

  float s[16];
  float4 vv[16];
#pragma unroll
  for (int j = 0; j < 16; j++) {
    int nb = __shfl(my, j);
    size_t base = (size_t)(bN + nb) * C_ + lane * 4;
    float4 k4 = *(const float4*)(kf + base);
    vv[j] = *(const float4*)(vf + base);
    float p = k4.x * q4.x + k4.y * q4.y + k4.z * q4.z + k4.w * q4.w;
    p += __shfl_xor(p, 1); p += __shfl_xor(p, 2); p += __shfl_xor(p, 4);
    s[j] = p * scale;                          // per-head score (8-lane groups)
  }
  float mx = s[0];
#pragma unroll
  for (int j = 1; j < 16; j++) mx = fmaxf(mx, s[j]);
  float den = 0.f;
#pragma unroll
  for (int j = 0; j < 16; j++) { s[j] = __expf(s[j] - mx); den += s[j]; }
  float inv = 1.0f / den;
  float4 o; o.x = 0.f; o.y = 0.f; o.z = 0.f; o.w = 0.f;
#pragma unroll
  for (int j = 0; j < 16; j++) {
    float w = s[j] * inv;
    o.x = fmaf(w, vv[j].x, o.x); o.y = fmaf(w, vv[j].y, o.y);
    o.z = fmaf(w, vv[j].z, o.z); o.w = fmaf(w, vv[j].w, o.w);
  }
  *(float4*)(out + (size_t)g * C_ + lane * 4) = o;
}

extern "C" void kernel_launch(void* const* d_in, const int* in_sizes, int n_in,
                              void* d_out, int out_size, void* d_ws, size_t ws_size,
                              hipStream_t stream) {
  const float* x  = (const float*)d_in[0];
  const float* Wq = (const float*)d_in[1];
  const float* bq = (const float*)d_in[2];
  const float* Wk = (const float*)d_in[3];
  const float* bk = (const float*)d_in[4];
  const float* Wv = (const float*)d_in[5];
  const float* bv = (const float*)d_in[6];
  float* out = (float*)d_out;

  char* ws = (char*)d_ws;
  float* sqp  = (float*)(ws + 0);              //   64 KB
  float* qf   = (float*)(ws + 65536);          //   16 MB
  float* kf   = (float*)(ws + 16842752);       //   16 MB
  float* vf   = (float*)(ws + 33619968);       //   16 MB
  float* pd   = (float*)(ws + 50397184);       //    4 MB
  int*   pi   = (int*)  (ws + 54591488);       //    4 MB
  int*   idxb = (int*)  (ws + 58785792);       //    1 MB (total ~57 MB)

  k_sq    <<<4096, 256, 0, stream>>>(x, sqp);
  k_proj  <<<768,  256, 0, stream>>>(x, Wq, Wk, Wv, bq, bk, bv, qf, kf, vf);
  k_knn   <<<512,  256, 0, stream>>>(x, sqp, pd, pi);
  k_kmerge<<<64,   256, 0, stream>>>(pd, pi, idxb);
  k_attn  <<<4096, 256, 0, stream>>>(qf, kf, vf, idxb, out);
}

// Round 3
// 677.588 us; speedup vs baseline: 2.1872x; 2.1872x over previous
//
#include <hip/hip_runtime.h>
#include <cstdint>
#include <cstddef>

#define N_ 4096
#define C_ 256

typedef _Float16 h8 __attribute__((ext_vector_type(8)));
typedef _Float16 h4 __attribute__((ext_vector_type(4)));
typedef float f4 __attribute__((ext_vector_type(4)));

// -------------------------------------- sq = sum x^2 ; split x -> f16 hi + lo
__global__ __launch_bounds__(256) void k_prep(const float* __restrict__ x,
                                              float* __restrict__ sq,
                                              _Float16* __restrict__ xh,
                                              _Float16* __restrict__ xl) {
  int wave = threadIdx.x >> 6, lane = threadIdx.x & 63;
  int row = blockIdx.x * 4 + wave;            // 0..16383
  size_t off = (size_t)row * C_ + lane * 4;
  float4 v = *(const float4*)(x + off);
  h4 hi; hi[0] = (_Float16)v.x; hi[1] = (_Float16)v.y;
         hi[2] = (_Float16)v.z; hi[3] = (_Float16)v.w;
  h4 lo; lo[0] = (_Float16)(v.x - (float)hi[0]); lo[1] = (_Float16)(v.y - (float)hi[1]);
         lo[2] = (_Float16)(v.z - (float)hi[2]); lo[3] = (_Float16)(v.w - (float)hi[3]);
  *(h4*)(xh + off) = hi;
  *(h4*)(xl + off) = lo;
  float s = v.x * v.x + v.y * v.y + v.z * v.z + v.w * v.w;
  s += __shfl_xor(s, 32); s += __shfl_xor(s, 16); s += __shfl_xor(s, 8);
  s += __shfl_xor(s, 4);  s += __shfl_xor(s, 2);  s += __shfl_xor(s, 1);
  if (lane == 0) sq[row] = s;
}

// ------------------------------------------------- q/k/v projections, fp32 VALU
__global__ __launch_bounds__(256) void k_proj(const float* __restrict__ x,
                                              const float* __restrict__ Wq,
                                              const float* __restrict__ Wk,
                                              const float* __restrict__ Wv,
                                              const float* __restrict__ bqp,
                                              const float* __restrict__ bkp,
                                              const float* __restrict__ bvp,
                                              float* __restrict__ qf,
                                              float* __restrict__ kf,
                                              float* __restrict__ vf) {
  __shared__ float As[32 * 132];
  __shared__ float Bs[32 * 132];
  int tid = threadIdx.x;
  int m  = blockIdx.x >> 8;                    // 0..2
  int rt = (blockIdx.x >> 1) & 127;            // 0..127
  int ct = blockIdx.x & 1;                     // 0..1
  const float* W  = (m == 0) ? Wq  : ((m == 1) ? Wk  : Wv);
  const float* bb = (m == 0) ? bqp : ((m == 1) ? bkp : bvp);
  float* dst      = (m == 0) ? qf  : ((m == 1) ? kf  : vf);
  int row0 = rt * 128, col0 = ct * 128;
  int ty = tid >> 4, tx = tid & 15;

  float acc[8][8];
#pragma unroll
  for (int i = 0; i < 8; i++)
#pragma unroll
    for (int j = 0; j < 8; j++) acc[i][j] = 0.f;

#pragma unroll 1
  for (int kc = 0; kc < 8; kc++) {
    __syncthreads();
    {
      int kk = tid & 31, rg = tid >> 5;
#pragma unroll
      for (int rr = 0; rr < 16; rr++) {
        int r = rr * 8 + rg;
        As[kk * 132 + r] = x[(size_t)(row0 + r) * C_ + kc * 32 + kk];
      }
      int c = tid & 127, kg = tid >> 7;
#pragma unroll
      for (int it = 0; it < 16; it++) {
        int kk2 = it * 2 + kg;
        Bs[kk2 * 132 + c] = W[(size_t)(kc * 32 + kk2) * C_ + col0 + c];
      }
    }
    __syncthreads();
#pragma unroll
    for (int kk = 0; kk < 32; kk++) {
      float4 a0 = *(float4*)(&As[kk * 132 + ty * 8]);
      float4 a1 = *(float4*)(&As[kk * 132 + ty * 8 + 4]);
      float4 b0 = *(float4*)(&Bs[kk * 132 + tx * 8]);
      float4 b1 = *(float4*)(&Bs[kk * 132 + tx * 8 + 4]);
      float av[8], bw[8];
      *(float4*)&av[0] = a0; *(float4*)&av[4] = a1;
      *(float4*)&bw[0] = b0; *(float4*)&bw[4] = b1;
#pragma unroll
      for (int i = 0; i < 8; i++)
#pragma unroll
        for (int j = 0; j < 8; j++) acc[i][j] = fmaf(av[i], bw[j], acc[i][j]);
    }
  }
#pragma unroll
  for (int i = 0; i < 8; i++) {
    size_t r = (size_t)(row0 + ty * 8 + i) * C_;
#pragma unroll
    for (int j4 = 0; j4 < 2; j4++) {
      int c0 = col0 + tx * 8 + j4 * 4;
      float4 o;
      o.x = acc[i][j4 * 4 + 0] + bb[c0 + 0];
      o.y = acc[i][j4 * 4 + 1] + bb[c0 + 1];
      o.z = acc[i][j4 * 4 + 2] + bb[c0 + 2];
      o.w = acc[i][j4 * 4 + 3] + bb[c0 + 3];
      *(float4*)(dst + r + c0) = o;
    }
  }
}

// ---------------- split-f16 MFMA distance GEMM + gated per-row top-16 (1 wave)
// wave = 32 target rows; sources: 1024-range split (s4), chunks of 32.
// bid = ((b*128 + tile)*4 + s4);  grid 2048 x 64 threads.
__global__ __launch_bounds__(64, 2) void k_knn(const _Float16* __restrict__ xh,
                                               const _Float16* __restrict__ xl,
                                               const float* __restrict__ sq,
                                               float* __restrict__ pd,
                                               int* __restrict__ pi) {
  __shared__ float sc[32 * 33];               // pad 33: scan reads conflict-free
  __shared__ float kd[32 * 17];               // pad 17
  __shared__ int   ki[32 * 17];

  int lane = threadIdx.x;
  int quad = lane >> 4, l16 = lane & 15;
  int bid = blockIdx.x;
  int s4   = bid & 3;
  int tile = (bid >> 2) & 127;
  int b    = bid >> 9;
  int bN = b * N_, n0 = tile * 32, src0g = s4 * 1024;

  if (lane < 32) {
#pragma unroll
    for (int p = 0; p < 16; p++) { kd[lane * 17 + p] = 1e38f; ki[lane * 17 + p] = 0; }
  }

  // A fragments: 32 rows x 256 k, hi+lo, in registers for the whole kernel
  h8 Ah[2][8], Al[2][8];
#pragma unroll
  for (int rt = 0; rt < 2; rt++)
#pragma unroll
    for (int kc = 0; kc < 8; kc++) {
      size_t off = (size_t)(bN + n0 + rt * 16 + l16) * C_ + kc * 32 + quad * 8;
      Ah[rt][kc] = *(const h8*)(xh + off);
      Al[rt][kc] = *(const h8*)(xl + off);
    }
  float sqT[2][4], thrR[2][4];
#pragma unroll
  for (int rt = 0; rt < 2; rt++)
#pragma unroll
    for (int i = 0; i < 4; i++) {
      sqT[rt][i] = sq[bN + n0 + rt * 16 + quad * 4 + i];
      thrR[rt][i] = 1e38f;
    }

#pragma unroll 1
  for (int ch = 0; ch < 32; ch++) {
    int src0 = src0g + ch * 32;
    float sqS[2];
#pragma unroll
    for (int ct = 0; ct < 2; ct++) sqS[ct] = sq[bN + src0 + ct * 16 + l16];

    f4 acc[2][2];
#pragma unroll
    for (int rt = 0; rt < 2; rt++)
#pragma unroll
      for (int ct = 0; ct < 2; ct++) acc[rt][ct] = f4{0.f, 0.f, 0.f, 0.f};

    h8 Bh[2][2], Bl[2][2];                    // double buffer [buf][ct]
#pragma unroll
    for (int ct = 0; ct < 2; ct++) {
      size_t off = (size_t)(bN + src0 + ct * 16 + l16) * C_ + quad * 8;
      Bh[0][ct] = *(const h8*)(xh + off);
      Bl[0][ct] = *(const h8*)(xl + off);
    }
#pragma unroll
    for (int kc = 0; kc < 8; kc++) {
      int cur = kc & 1, nxt = cur ^ 1;
      if (kc < 7) {
#pragma unroll
        for (int ct = 0; ct < 2; ct++) {
          size_t off = (size_t)(bN + src0 + ct * 16 + l16) * C_ + (kc + 1) * 32 + quad * 8;
          Bh[nxt][ct] = *(const h8*)(xh + off);
          Bl[nxt][ct] = *(const h8*)(xl + off);
        }
      }
#pragma unroll
      for (int rt = 0; rt < 2; rt++)
#pragma unroll
        for (int ct = 0; ct < 2; ct++) {
          acc[rt][ct] = __builtin_amdgcn_mfma_f32_16x16x32_f16(Ah[rt][kc], Bh[cur][ct], acc[rt][ct], 0, 0, 0);
          acc[rt][ct] = __builtin_amdgcn_mfma_f32_16x16x32_f16(Ah[rt][kc], Bl[cur][ct], acc[rt][ct], 0, 0, 0);
          acc[rt][ct] = __builtin_amdgcn_mfma_f32_16x16x32_f16(Al[rt][kc], Bh[cur][ct], acc[rt][ct], 0, 0, 0);
        }
    }

    // gate: does any lane hold a candidate beating its (stale-safe) threshold?
    bool anyp = false;
#pragma unroll
    for (int rt = 0; rt < 2; rt++)
#pragma unroll
      for (int ct = 0; ct < 2; ct++)
#pragma unroll
        for (int i = 0; i < 4; i++) {
          float d2 = sqT[rt][i] + sqS[ct] - 2.0f * acc[rt][ct][i];
          if (n0 + rt * 16 + quad * 4 + i == src0 + ct * 16 + l16) d2 = 1e38f;
          anyp |= (d2 < thrR[rt][i]);
        }
    if (__any(anyp)) {
#pragma unroll
      for (int rt = 0; rt < 2; rt++)
#pragma unroll
        for (int ct = 0; ct < 2; ct++)
#pragma unroll
          for (int i = 0; i < 4; i++) {
            float d2 = sqT[rt][i] + sqS[ct] - 2.0f * acc[rt][ct][i];
            if (n0 + rt * 16 + quad * 4 + i == src0 + ct * 16 + l16) d2 = 1e38f;
            sc[(rt * 16 + quad * 4 + i) * 33 + ct * 16 + l16] = d2;
          }
      if (lane < 32) {                         // wave-coherent LDS: no barrier
        int row = lane;
        float thr = kd[row * 17 + 15];
#pragma unroll 1
        for (int c = 0; c < 32; c++) {
          float d = sc[row * 33 + c];
          if (d < thr) {
            int p = 15;
            while (p > 0 && kd[row * 17 + p - 1] > d) {
              kd[row * 17 + p] = kd[row * 17 + p - 1];
              ki[row * 17 + p] = ki[row * 17 + p - 1];
              p--;
            }
            kd[row * 17 + p] = d;
            ki[row * 17 + p] = src0 + c;
            thr = kd[row * 17 + 15];
          }
        }
      }
#pragma unroll
      for (int rt = 0; rt < 2; rt++)
#pragma unroll
        for (int i = 0; i < 4; i++)
          thrR[rt][i] = kd[(rt * 16 + quad * 4 + i) * 17 + 15];
    }
  }

  if (lane < 32) {
#pragma unroll
    for (int p = 0; p < 16; p++) {
      size_t e = ((size_t)bid * 32 + lane) * 16 + p;
      pd[e] = kd[lane * 17 + p];
      pi[e] = ki[lane * 17 + p];
    }
  }
}

// ------------------------------------- merge 4 partial sorted lists -> top-16
__global__ __launch_bounds__(256) void k_kmerge(const float* __restrict__ pd,
                                                const int* __restrict__ pi,
                                                int* __restrict__ idxo) {
  int g = blockIdx.x * 256 + threadIdx.x;      // 0..16383
  int b = g >> 12, n = g & 4095;
  int tile = n >> 5, r = n & 31;
  int base[4], p[4];
  float hd[4];
#pragma unroll
  for (int s = 0; s < 4; s++) {
    base[s] = (((b * 128 + tile) * 4 + s) * 32 + r) * 16;
    p[s] = 0;
    hd[s] = pd[base[s]];
  }
#pragma unroll
  for (int k = 0; k < 16; k++) {
    int bs = 0; float bd = hd[0];
#pragma unroll
    for (int s = 1; s < 4; s++) if (hd[s] < bd) { bd = hd[s]; bs = s; }
    idxo[(size_t)g * 16 + k] = pi[base[bs] + p[bs]];
    p[bs]++;
    hd[bs] = (p[bs] < 16) ? pd[base[bs] + p[bs]] : 1e38f;
  }
}

// -------------------------------------------- gather + attention (wave/node)
__global__ __launch_bounds__(256) void k_attn(const float* __restrict__ qf,
                                              const float* __restrict__ kf,
                                              const float* __restrict__ vf,
                                              const int* __restrict__ idxv,
                                              float* __restrict__ out) {
  int wave = threadIdx.x >> 6, lane = threadIdx.x & 63;
  int g = blockIdx.x * 4 + wave;               // node 0..16383
  int bN = (g >> 12) << 12;
  float4 q4 = *(const float4*)(qf + (size_t)g * C_ + lane * 4);
  int my = idxv[(size_t)g * 16 + (lane & 15)];
  const float scale = 0.17677669529663687f;    // 1/sqrt(32)

  float s[16];
  float4 vv[16];
#pragma unroll
  for (int j = 0; j < 16; j++) {
    int nb = __shfl(my, j);
    size_t base = (size_t)(bN + nb) * C_ + lane * 4;
    float4 k4 = *(const float4*)(kf + base);
    vv[j] = *(const float4*)(vf + base);
    float p = k4.x * q4.x + k4.y * q4.y + k4.z * q4.z + k4.w * q4.w;
    p += __shfl_xor(p, 1); p += __shfl_xor(p, 2); p += __shfl_xor(p, 4);
    s[j] = p * scale;
  }
  float mx = s[0];
#pragma unroll
  for (int j = 1; j < 16; j++) mx = fmaxf(mx, s[j]);
  float den = 0.f;
#pragma unroll
  for (int j = 0; j < 16; j++) { s[j] = __expf(s[j] - mx); den += s[j]; }
  float inv = 1.0f / den;
  float4 o; o.x = 0.f; o.y = 0.f; o.z = 0.f; o.w = 0.f;
#pragma unroll
  for (int j = 0; j < 16; j++) {
    float w = s[j] * inv;
    o.x = fmaf(w, vv[j].x, o.x); o.y = fmaf(w, vv[j].y, o.y);
    o.z = fmaf(w, vv[j].z, o.z); o.w = fmaf(w, vv[j].w, o.w);
  }
  *(float4*)(out + (size_t)g * C_ + lane * 4) = o;
}

extern "C" void kernel_launch(void* const* d_in, const int* in_sizes, int n_in,
                              void* d_out, int out_size, void* d_ws, size_t ws_size,
                              hipStream_t stream) {
  const float* x  = (const float*)d_in[0];
  const float* Wq = (const float*)d_in[1];
  const float* bq = (const float*)d_in[2];
  const float* Wk = (const float*)d_in[3];
  const float* bk = (const float*)d_in[4];
  const float* Wv = (const float*)d_in[5];
  const float* bv = (const float*)d_in[6];
  float* out = (float*)d_out;

  char* ws = (char*)d_ws;
  float*     sqp  = (float*)(ws + 0);                //  64 KB
  _Float16*  xh   = (_Float16*)(ws + 65536);         //   8 MB
  _Float16*  xl   = (_Float16*)(ws + 8454144);       //   8 MB
  float*     qf   = (float*)(ws + 16842752);         //  16 MB
  float*     kf   = (float*)(ws + 33619968);         //  16 MB
  float*     vf   = (float*)(ws + 50397184);         //  16 MB
  float*     pd   = (float*)(ws + 67174400);         //   4 MB
  int*       pi   = (int*)  (ws + 71368704);         //   4 MB
  int*       idxb = (int*)  (ws + 75563008);         //   1 MB (total ~73 MB)

  k_prep  <<<4096, 256, 0, stream>>>(x, sqp, xh, xl);
  k_proj  <<<768,  256, 0, stream>>>(x, Wq, Wk, Wv, bq, bk, bv, qf, kf, vf);
  k_knn   <<<2048, 64,  0, stream>>>(xh, xl, sqp, pd, pi);
  k_kmerge<<<64,   256, 0, stream>>>(pd, pi, idxb);
  k_attn  <<<4096, 256, 0, stream>>>(qf, kf, vf, idxb, out);
}